// Round 6
// baseline (259.205 us; speedup 1.0000x reference)
//
#include <hip/hip_runtime.h>
#include <hip/hip_bf16.h>
#include <cstdint>

typedef __bf16 bf16;
typedef bf16 bf16x2 __attribute__((ext_vector_type(2)));
typedef bf16 bf16x4 __attribute__((ext_vector_type(4)));
typedef bf16 bf16x8 __attribute__((ext_vector_type(8)));
typedef _Float16 f16;
typedef f16 f16x2 __attribute__((ext_vector_type(2)));
typedef f16 f16x4 __attribute__((ext_vector_type(4)));
typedef f16 f16x8 __attribute__((ext_vector_type(8)));
typedef float f32x4 __attribute__((ext_vector_type(4)));

#define MFMA16(a, b, c) __builtin_amdgcn_mfma_f32_16x16x32_bf16((a), (b), (c), 0, 0, 0)
#define MFMA16H(a, b, c) __builtin_amdgcn_mfma_f32_16x16x16f16((a), (b), (c), 0, 0, 0)

// 0.125 * log2(e): folded into Q at the QKV-GEMM epilogue
#define QSCALE 0.18033688011112042f

// async global->LDS DMA, 16B/lane. LDS dest must be wave-uniform base + lane*16.
__device__ inline void async16(const bf16* g, bf16* l) {
  __builtin_amdgcn_global_load_lds(
      (const __attribute__((address_space(1))) void*)g,
      (__attribute__((address_space(3))) void*)l, 16, 0, 0);
}

// ------------------------------------------------------------------
// fused cast fp32 -> bf16 for all four inputs (one launch)
// ------------------------------------------------------------------
__global__ void cast_all(const float* __restrict__ x, const float* __restrict__ wq,
                         const float* __restrict__ wkv, const float* __restrict__ wp,
                         bf16* __restrict__ xb, bf16* __restrict__ w1b,
                         bf16* __restrict__ wpb) {
  const int i = blockIdx.x * blockDim.x + threadIdx.x;
  const float4* src;
  bf16x4* dst;
  int idx;
  if (i < 2097152) {
    src = (const float4*)x; dst = (bf16x4*)xb; idx = i;
  } else if (i < 2359296) {
    src = (const float4*)wq; dst = (bf16x4*)w1b; idx = i - 2097152;
  } else if (i < 2490368) {
    src = (const float4*)wkv; dst = (bf16x4*)(w1b + 1048576); idx = i - 2359296;
  } else {
    src = (const float4*)wp; dst = (bf16x4*)wpb; idx = i - 2490368;
  }
  const float4 v = src[idx];
  bf16x4 o;
  o.x = (bf16)v.x; o.y = (bf16)v.y; o.z = (bf16)v.z; o.w = (bf16)v.w;
  dst[idx] = o;
}

// ------------------------------------------------------------------
// GEMM1: C[m,e] = sum_c x[m,c] * W1[e,c]   (M=8192, N=1536, K=1024)
// Q pre-scaled by QSCALE (bf16), K bf16, V stored as f16 for the
// f16 PV MFMA in attention.
// ------------------------------------------------------------------
__global__ __launch_bounds__(256, 2)
void gemm_qkv(const bf16* __restrict__ A, const bf16* __restrict__ B,
              bf16* __restrict__ qb, bf16* __restrict__ kb, f16* __restrict__ vb) {
  constexpr int K = 1024;
  __shared__ bf16 sA[128 * 64];
  __shared__ bf16 sB[128 * 64];
  const int tid = threadIdx.x;
  const int lane = tid & 63, wid = tid >> 6;
  const int col = lane & 15, quad = lane >> 4;
  const int wm = wid >> 1, wn = wid & 1;
  const int m0 = blockIdx.y * 128, n0 = blockIdx.x * 128;
  const int c7 = col & 7;

  f32x4 acc[4][4];
  const f32x4 z = {0.f, 0.f, 0.f, 0.f};
#pragma unroll
  for (int mi = 0; mi < 4; mi++)
#pragma unroll
    for (int ni = 0; ni < 4; ni++) acc[mi][ni] = z;

  for (int k0 = 0; k0 < K; k0 += 64) {
    __syncthreads();
#pragma unroll
    for (int c = 0; c < 4; ++c) {
      const int idx = c * 256 + tid;
      const int row = idx >> 3, kc = idx & 7;
      const int gkc = kc ^ (row & 7);
      async16(&A[(size_t)(m0 + row) * K + k0 + gkc * 8], &sA[idx * 8]);
      async16(&B[(size_t)(n0 + row) * K + k0 + gkc * 8], &sB[idx * 8]);
    }
    __syncthreads();  // vmcnt(0) drain: DMA complete
#pragma unroll
    for (int ks = 0; ks < 2; ++ks) {
      bf16x8 af[4], bfr[4];
#pragma unroll
      for (int i = 0; i < 4; i++)
        af[i] = *(const bf16x8*)&sA[(wm * 64 + i * 16 + col) * 64 +
                                    (((ks * 4 + quad) ^ c7) << 3)];
#pragma unroll
      for (int i = 0; i < 4; i++)
        bfr[i] = *(const bf16x8*)&sB[(wn * 64 + i * 16 + col) * 64 +
                                     (((ks * 4 + quad) ^ c7) << 3)];
#pragma unroll
      for (int mi = 0; mi < 4; mi++)
#pragma unroll
        for (int ni = 0; ni < 4; ni++)
          acc[mi][ni] = MFMA16(af[mi], bfr[ni], acc[mi][ni]);
    }
  }
#pragma unroll
  for (int mi = 0; mi < 4; mi++) {
#pragma unroll
    for (int ni = 0; ni < 4; ni++) {
      const int e = n0 + wn * 64 + ni * 16 + col;
#pragma unroll
      for (int r = 0; r < 4; r++) {
        const int m = m0 + wm * 64 + mi * 16 + quad * 4 + r;
        const int bb = m >> 11, t = m & 2047;
        if (e < 1024) {
          qb[(((size_t)bb * 16 + (e >> 6)) * 2048 + t) * 64 + (e & 63)] =
              (bf16)(acc[mi][ni][r] * QSCALE);
        } else if (e < 1280) {
          const int f = e - 1024;
          kb[(((size_t)bb * 4 + (f >> 6)) * 2048 + t) * 64 + (f & 63)] =
              (bf16)acc[mi][ni][r];
        } else {
          const int f = e - 1280;
          vb[(((size_t)bb * 4 + (f >> 6)) * 2048 + t) * 64 + (f & 63)] =
              (f16)acc[mi][ni][r];
        }
      }
    }
  }
}

// ------------------------------------------------------------------
// GEMM2: out[m,e] = sum_c AO[m,c] * Wproj[e,c] + bias[e]  (fp32 out)
// ------------------------------------------------------------------
__global__ __launch_bounds__(256, 2)
void gemm_proj(const bf16* __restrict__ A, const bf16* __restrict__ B,
               const float* __restrict__ bias, float* __restrict__ out) {
  constexpr int K = 1024;
  __shared__ bf16 sA[128 * 64];
  __shared__ bf16 sB[128 * 64];
  const int tid = threadIdx.x;
  const int lane = tid & 63, wid = tid >> 6;
  const int col = lane & 15, quad = lane >> 4;
  const int wm = wid >> 1, wn = wid & 1;
  const int m0 = blockIdx.y * 128, n0 = blockIdx.x * 128;
  const int c7 = col & 7;

  f32x4 acc[4][4];
  const f32x4 z = {0.f, 0.f, 0.f, 0.f};
#pragma unroll
  for (int mi = 0; mi < 4; mi++)
#pragma unroll
    for (int ni = 0; ni < 4; ni++) acc[mi][ni] = z;

  for (int k0 = 0; k0 < K; k0 += 64) {
    __syncthreads();
#pragma unroll
    for (int c = 0; c < 4; ++c) {
      const int idx = c * 256 + tid;
      const int row = idx >> 3, kc = idx & 7;
      const int gkc = kc ^ (row & 7);
      async16(&A[(size_t)(m0 + row) * K + k0 + gkc * 8], &sA[idx * 8]);
      async16(&B[(size_t)(n0 + row) * K + k0 + gkc * 8], &sB[idx * 8]);
    }
    __syncthreads();
#pragma unroll
    for (int ks = 0; ks < 2; ++ks) {
      bf16x8 af[4], bfr[4];
#pragma unroll
      for (int i = 0; i < 4; i++)
        af[i] = *(const bf16x8*)&sA[(wm * 64 + i * 16 + col) * 64 +
                                    (((ks * 4 + quad) ^ c7) << 3)];
#pragma unroll
      for (int i = 0; i < 4; i++)
        bfr[i] = *(const bf16x8*)&sB[(wn * 64 + i * 16 + col) * 64 +
                                     (((ks * 4 + quad) ^ c7) << 3)];
#pragma unroll
      for (int mi = 0; mi < 4; mi++)
#pragma unroll
        for (int ni = 0; ni < 4; ni++)
          acc[mi][ni] = MFMA16(af[mi], bfr[ni], acc[mi][ni]);
    }
  }
#pragma unroll
  for (int mi = 0; mi < 4; mi++) {
#pragma unroll
    for (int ni = 0; ni < 4; ni++) {
      const int e = n0 + wn * 64 + ni * 16 + col;
      const float be = bias[e];
#pragma unroll
      for (int r = 0; r < 4; r++) {
        const int m = m0 + wm * 64 + mi * 16 + quad * 4 + r;
        out[(size_t)m * 1024 + e] = acc[mi][ni][r] + be;
      }
    }
  }
}

// ------------------------------------------------------------------
// Flash attention v3 structure:
//  - QK^T (bf16 x32 MFMA) with K A-frags loaded DIRECT from global
//    (coalesced, L2-hot) — no K LDS, no barrier on the QK path.
//  - S^T C-layout == B-operand layout of 16x16x16 MFMA, so PV runs as
//    O^T = V^T P^T in f16 with P packed straight from registers.
//  - V is the only LDS-staged tensor ([d][kv] stride 72, dbuf,
//    one barrier per chunk).  Row sums l via ones-A f16 MFMA,
//    landing in C-layout at col=q — matches O^T epilogue exactly.
// ------------------------------------------------------------------
__global__ __launch_bounds__(256, 2)
void attn_alibi(const bf16* __restrict__ qb, const bf16* __restrict__ kbp,
                const f16* __restrict__ vbp, bf16* __restrict__ ob) {
  __shared__ f16 sVt[2][64 * 72];  // [buf][d][kv]
  const int tid = threadIdx.x;
  const int lane = tid & 63, wid = tid >> 6;
  const int col = lane & 15, quad = lane >> 4;
  const int bh = blockIdx.y;
  const int b = bh >> 4, h = bh & 15, kvh = h & 3;
  const int qbase = __builtin_amdgcn_readfirstlane(blockIdx.x * 256 + wid * 64);

  const bf16* qptr = qb + ((size_t)(b * 16 + h) * 2048 + qbase) * 64;
  const bf16* kptr = kbp + ((size_t)(b * 4 + kvh) * 2048) * 64;
  const f16* vptr = vbp + ((size_t)(b * 4 + kvh) * 2048) * 64;

  // Q resident as B-operand frags (x32): B[n=q(col)][k=d=ks*32+quad*8+j]
  bf16x8 bq[4][2];
#pragma unroll
  for (int ni = 0; ni < 4; ni++)
#pragma unroll
    for (int ks = 0; ks < 2; ks++)
      bq[ni][ks] = *(const bf16x8*)&qptr[(ni * 16 + col) * 64 + ks * 32 + quad * 8];

  f16x4 ones;
#pragma unroll
  for (int j = 0; j < 4; j++) ones[j] = (f16)1.0f;

  f32x4 OT[4][4];  // O^T[d-tile nd][q-tile ni]; lane: d=quad*4+r, q=col
  f32x4 lC[4];     // l per q-tile, C-layout (all rows identical)
  const f32x4 z = {0.f, 0.f, 0.f, 0.f};
#pragma unroll
  for (int nd = 0; nd < 4; nd++) {
    lC[nd] = z;
#pragma unroll
    for (int ni = 0; ni < 4; ni++) OT[nd][ni] = z;
  }

  const float cb = exp2f(-0.5f * (float)(h + 1)) * QSCALE;  // bias slope, exp2 dom
  const int qoff = quad * 4 - col;

  // K A-frag prefetch (x32 layout): A[m=kv=mi*16+col][k=ks*32+quad*8+j]
  bf16x8 ak[4][2];
#pragma unroll
  for (int mi = 0; mi < 4; mi++)
#pragma unroll
    for (int ks = 0; ks < 2; ks++)
      ak[mi][ks] = *(const bf16x8*)&kptr[(size_t)(mi * 16 + col) * 64 + ks * 32 + quad * 8];

  // V staging map: thread handles kv-row pair (2p, 2p+1), d-chunk kcv*8..+7
  const int pv = tid & 31, kcv = tid >> 5;
  f16x8 vr0 = *(const f16x8*)&vptr[(size_t)(2 * pv) * 64 + kcv * 8];
  f16x8 vr1 = *(const f16x8*)&vptr[(size_t)(2 * pv + 1) * 64 + kcv * 8];

  int bufi = 0;
  for (int c0 = 0; c0 < 2048; c0 += 64, bufi ^= 1) {
    // commit V transposed: sVt[d][kv] <- pairs (2p,2p+1); banks 2-way free
    f16* sv = sVt[bufi];
#pragma unroll
    for (int j = 0; j < 8; j++) {
      f16x2 pr;
      pr.x = vr0[j];
      pr.y = vr1[j];
      *(f16x2*)&sv[(kcv * 8 + j) * 72 + 2 * pv] = pr;
    }
    __syncthreads();  // sVt[bufi] visible; other buffer now free

    // prefetch next chunk's K frags + V rows (covered by this chunk's compute)
    const int cn = (c0 + 64 < 2048) ? c0 + 64 : 0;
    bf16x8 akn[4][2];
#pragma unroll
    for (int mi = 0; mi < 4; mi++)
#pragma unroll
      for (int ks = 0; ks < 2; ks++)
        akn[mi][ks] = *(const bf16x8*)&kptr[(size_t)(cn + mi * 16 + col) * 64 +
                                            ks * 32 + quad * 8];
    f16x8 vr0n = *(const f16x8*)&vptr[(size_t)(cn + 2 * pv) * 64 + kcv * 8];
    f16x8 vr1n = *(const f16x8*)&vptr[(size_t)(cn + 2 * pv + 1) * 64 + kcv * 8];

    // S^T = K Q^T (exp2 domain; rows kv=quad*4+r+16*kb, cols q=col+16*ni)
    f32x4 S[4][4];
#pragma unroll
    for (int kb = 0; kb < 4; kb++)
#pragma unroll
      for (int ni = 0; ni < 4; ni++) S[kb][ni] = z;
#pragma unroll
    for (int ks = 0; ks < 2; ks++)
#pragma unroll
      for (int kb = 0; kb < 4; kb++)
#pragma unroll
        for (int ni = 0; ni < 4; ni++)
          S[kb][ni] = MFMA16(ak[kb][ks], bq[ni][ks], S[kb][ni]);

    // per 16-kv block: bias + exp2 -> f16 P-frags (B-layout!) -> PV + l
#pragma unroll
    for (int kb = 0; kb < 4; kb++) {
      f16x4 pf[4];
#pragma unroll
      for (int ni = 0; ni < 4; ni++) {
        const int U = c0 + kb * 16 - qbase - ni * 16;  // wave-uniform
        f32x4 p;
        if (U <= -15) {
          const float bb = cb * (float)(U + qoff);
#pragma unroll
          for (int r = 0; r < 4; r++)
            p[r] = __builtin_amdgcn_exp2f(S[kb][ni][r] + (bb + cb * (float)r));
        } else if (U >= 16) {
#pragma unroll
          for (int r = 0; r < 4; r++)
            p[r] = __builtin_amdgcn_exp2f(S[kb][ni][r]);
        } else {
          const float relf = (float)(U + qoff);
#pragma unroll
          for (int r = 0; r < 4; r++) {
            const float rr = relf + (float)r;
            const float bb = (rr <= 0.f) ? cb * rr : 0.f;
            p[r] = __builtin_amdgcn_exp2f(S[kb][ni][r] + bb);
          }
        }
#pragma unroll
        for (int r = 0; r < 4; r++) pf[ni][r] = (f16)p[r];
      }
      // V^T A-frags: A[m=d=nd*16+col][k=kv=kb*16+quad*4+j]  (b64, bank-free)
      f16x4 av[4];
#pragma unroll
      for (int nd = 0; nd < 4; nd++)
        av[nd] = *(const f16x4*)&sv[(nd * 16 + col) * 72 + kb * 16 + quad * 4];
#pragma unroll
      for (int ni = 0; ni < 4; ni++) {
#pragma unroll
        for (int nd = 0; nd < 4; nd++)
          OT[nd][ni] = MFMA16H(av[nd], pf[ni], OT[nd][ni]);
        lC[ni] = MFMA16H(ones, pf[ni], lC[ni]);
      }
    }

    // rotate prefetch registers
#pragma unroll
    for (int mi = 0; mi < 4; mi++)
#pragma unroll
      for (int ks = 0; ks < 2; ks++) ak[mi][ks] = akn[mi][ks];
    vr0 = vr0n;
    vr1 = vr1n;
  }

  // epilogue: lane holds q=ni*16+col (matches lC), d=nd*16+quad*4+r
#pragma unroll
  for (int ni = 0; ni < 4; ni++) {
    const float inv = 1.0f / lC[ni][0];
    const size_t rowb = ((size_t)b * 2048 + qbase + ni * 16 + col) * 1024 + h * 64;
#pragma unroll
    for (int nd = 0; nd < 4; nd++) {
      bf16x4 w;
#pragma unroll
      for (int r = 0; r < 4; r++) w[r] = (bf16)(OT[nd][ni][r] * inv);
      *(bf16x4*)&ob[rowb + nd * 16 + quad * 4] = w;
    }
  }
}

// ------------------------------------------------------------------
extern "C" void kernel_launch(void* const* d_in, const int* in_sizes, int n_in,
                              void* d_out, int out_size, void* d_ws, size_t ws_size,
                              hipStream_t stream) {
  const float* x     = (const float*)d_in[0];
  const float* Wq    = (const float*)d_in[1];
  const float* Wkv   = (const float*)d_in[2];
  const float* Wproj = (const float*)d_in[3];
  const float* bproj = (const float*)d_in[4];
  float* out = (float*)d_out;

  bf16* xb  = (bf16*)d_ws;            // 8192*1024
  bf16* w1b = xb  + 8388608;          // 1536*1024
  bf16* wpb = w1b + 1572864;          // 1024*1024
  bf16* qb  = wpb + 1048576;          // [4,16,2048,64]
  bf16* kb  = qb  + 8388608;          // [4,4,2048,64]
  f16*  vb  = (f16*)(kb + 2097152);   // [4,4,2048,64] (f16)
  bf16* aob = (bf16*)(vb + 2097152);  // [4,2048,1024]

  cast_all<<<10752, 256, 0, stream>>>(x, Wq, Wkv, Wproj, xb, w1b, wpb);
  gemm_qkv<<<dim3(12, 64), 256, 0, stream>>>(xb, w1b, qb, kb, vb);
  attn_alibi<<<dim3(8, 64), 256, 0, stream>>>(qb, kb, vb, aob);
  gemm_proj<<<dim3(8, 64), 256, 0, stream>>>(aob, wpb, bproj, out);
}